// Round 1
// baseline (1002.084 us; speedup 1.0000x reference)
//
#include <hip/hip_runtime.h>
#include <hip/hip_bf16.h>

namespace {

constexpr int NN = 50000;
constexpr int NE = 800000;

typedef __attribute__((ext_vector_type(8))) short bf16x8;
typedef __attribute__((ext_vector_type(4))) float f32x4;

__device__ __forceinline__ short f2bf(float f) {
  __hip_bfloat16 h = __float2bfloat16(f);
  union U { __hip_bfloat16 h; short s; } u;
  u.h = h;
  return u.s;
}
__device__ __forceinline__ float bf2f(short s) {
  union U { unsigned int u; float f; } v;
  v.u = ((unsigned int)(unsigned short)s) << 16;
  return v.f;
}

// Repack weight W [din][dout] (f32, row-major) into bf16 MFMA B-fragment order:
// element gid = ((t*nK + kc)*64 + lane)*8 + j  holds  W[k][n],
//   n = t*16 + (lane&15), k = kc*32 + (lane>>4)*8 + j.
// Kernel-side: one 16B load per lane at Wf + (t*nK+kc)*512 + lane*8 -> fully coalesced 1KB.
__global__ __launch_bounds__(256) void wfrag_kernel(const float* __restrict__ W,
                                                    short* __restrict__ Wf,
                                                    int din, int dout) {
  int gid = blockIdx.x * 256 + threadIdx.x;
  if (gid >= din * dout) return;
  int j = gid & 7;
  int l = (gid >> 3) & 63;
  int rest = gid >> 9;
  int nK = din >> 5;
  int kc = rest % nK;
  int t = rest / nK;
  int n = t * 16 + (l & 15);
  int k = kc * 32 + (l >> 4) * 8 + j;
  Wf[gid] = f2bf(W[(size_t)k * dout + n]);
}

// ---------- CSR build ----------
__global__ __launch_bounds__(256) void hist_kernel(const int* __restrict__ edst,
                                                   int* __restrict__ deg) {
  int e = blockIdx.x * 256 + threadIdx.x;
  if (e < NE) atomicAdd(&deg[edst[e]], 1);
}

__global__ __launch_bounds__(256) void scan1_kernel(const int* __restrict__ deg,
                                                    int* __restrict__ excl,
                                                    int* __restrict__ bsum, int N) {
  __shared__ int s[256];
  int tid = threadIdx.x;
  int i = blockIdx.x * 256 + tid;
  int v = (i < N) ? deg[i] : 0;
  s[tid] = v;
  __syncthreads();
  for (int d = 1; d < 256; d <<= 1) {
    int t = (tid >= d) ? s[tid - d] : 0;
    __syncthreads();
    s[tid] += t;
    __syncthreads();
  }
  if (i < N) excl[i] = s[tid] - v;
  if (tid == 255) bsum[blockIdx.x] = s[255];
}

__global__ __launch_bounds__(256) void scan2_kernel(const int* __restrict__ bsum,
                                                    int* __restrict__ boff, int nb) {
  __shared__ int s[256];
  int tid = threadIdx.x;
  int v = (tid < nb) ? bsum[tid] : 0;
  s[tid] = v;
  __syncthreads();
  for (int d = 1; d < 256; d <<= 1) {
    int t = (tid >= d) ? s[tid - d] : 0;
    __syncthreads();
    s[tid] += t;
    __syncthreads();
  }
  if (tid <= nb) boff[tid] = s[tid] - v;  // exclusive; boff[nb] = total
}

__global__ __launch_bounds__(256) void scan3_kernel(const int* __restrict__ excl,
                                                    const int* __restrict__ boff,
                                                    int* __restrict__ row_start,
                                                    int N, int nb) {
  int i = blockIdx.x * 256 + threadIdx.x;
  if (i < N) row_start[i] = excl[i] + boff[i >> 8];
  else if (i == N) row_start[N] = boff[nb];
}

__global__ __launch_bounds__(256) void fill_kernel(const int* __restrict__ esrc,
                                                   const int* __restrict__ edst,
                                                   const int* __restrict__ row_start,
                                                   int* __restrict__ cursor,
                                                   int* __restrict__ adj) {
  int e = blockIdx.x * 256 + threadIdx.x;
  if (e >= NE) return;
  int d = edst[e];
  int p = atomicAdd(&cursor[d], 1);
  adj[row_start[d] + p] = esrc[e];
}

// ---------- segment-sum via CSR gather: one wave per node ----------
__global__ __launch_bounds__(256) void agg_kernel(const float* __restrict__ y,
                                                  const int* __restrict__ row_start,
                                                  const int* __restrict__ adj,
                                                  float* __restrict__ agg) {
  int gid = blockIdx.x * 256 + threadIdx.x;
  int n = gid >> 6;
  if (n >= NN) return;
  int lane = gid & 63;
  float ax = 0.f, ay = 0.f;
  int s0 = row_start[n], s1 = row_start[n + 1];
  for (int i = s0; i < s1; ++i) {
    int s = adj[i];  // wave-uniform
    float2 v = *reinterpret_cast<const float2*>(y + (size_t)s * 128 + lane * 2);
    ax += v.x;
    ay += v.y;
  }
  float2 o;
  o.x = ax;
  o.y = ay;
  *reinterpret_cast<float2*>(agg + (size_t)n * 128 + lane * 2) = o;
}

// ---------- MFMA helpers ----------
// Tile layout: [128 rows][128 bf16 cols], row stride 256B, XOR swizzle ((row&7)<<4)
// on the 16B granule -> conflict-free ds_read_b128 A-fragments.
template <int NKC, int NT>
__device__ __forceinline__ void gemm_tile(const char* tb, int rbase, int lane,
                                          const short* __restrict__ Wf,
                                          f32x4 (&acc)[2][NT]) {
#pragma unroll
  for (int kc = 0; kc < NKC; ++kc) {
    bf16x8 a[2];
#pragma unroll
    for (int m = 0; m < 2; ++m) {
      int row = rbase + m * 16 + (lane & 15);
      int off = (row * 256 + kc * 64 + (lane >> 4) * 16) ^ ((row & 7) << 4);
      a[m] = *reinterpret_cast<const bf16x8*>(tb + off);
    }
#pragma unroll
    for (int t = 0; t < NT; ++t) {
      bf16x8 b = *reinterpret_cast<const bf16x8*>(Wf + (t * NKC + kc) * 512 + lane * 8);
      acc[0][t] = __builtin_amdgcn_mfma_f32_16x16x32_bf16(a[0], b, acc[0][t], 0, 0, 0);
      acc[1][t] = __builtin_amdgcn_mfma_f32_16x16x32_bf16(a[1], b, acc[1][t], 0, 0, 0);
    }
  }
}

template <int NT, bool RELU>
__device__ __forceinline__ void epi_tile(char* tb, int rbase, int lane,
                                         const float* __restrict__ bias,
                                         f32x4 (&acc)[2][NT]) {
#pragma unroll
  for (int t = 0; t < NT; ++t) {
    int col = t * 16 + (lane & 15);
    float bb = bias[col];
#pragma unroll
    for (int m = 0; m < 2; ++m) {
#pragma unroll
      for (int i = 0; i < 4; ++i) {
        int row = rbase + m * 16 + (lane >> 4) * 4 + i;
        float h = acc[m][t][i] + bb;
        if (RELU) h = fmaxf(h, 0.f);
        int off = (row * 256 + col * 2) ^ ((row & 7) << 4);
        *reinterpret_cast<short*>(tb + off) = f2bf(h);
      }
    }
  }
}

// ---------- node MLP: out = relu(X@W1+b1)@W2+b2 (+skip), K=128 ----------
template <int NOUT, bool SKIP>
__global__ __launch_bounds__(256) void mlp_node(const float* __restrict__ X,
                                                const short* __restrict__ W1f,
                                                const float* __restrict__ b1,
                                                const short* __restrict__ W2f,
                                                const float* __restrict__ b2,
                                                const float* __restrict__ skip,
                                                float* __restrict__ out, int nrows) {
  __shared__ alignas(16) short tile[128 * 128];
  char* tb = reinterpret_cast<char*>(tile);
  const int tid = threadIdx.x;
  const int lane = tid & 63;
  const int wave = tid >> 6;
  const int row0 = blockIdx.x * 128;
  const f32x4 vzero = {0.f, 0.f, 0.f, 0.f};

  // stage 128 rows x 128 f32 -> bf16 tile (coalesced float4 loads)
#pragma unroll
  for (int it = 0; it < 16; ++it) {
    int r = it * 8 + (tid >> 5);
    int f4 = tid & 31;
    int gr = row0 + r;
    float4 v = make_float4(0.f, 0.f, 0.f, 0.f);
    if (gr < nrows) v = *reinterpret_cast<const float4*>(X + (size_t)gr * 128 + f4 * 4);
    short4 p;
    p.x = f2bf(v.x); p.y = f2bf(v.y); p.z = f2bf(v.z); p.w = f2bf(v.w);
    int off = (r * 256 + f4 * 8) ^ ((r & 7) << 4);
    *reinterpret_cast<short4*>(tb + off) = p;
  }
  __syncthreads();
  // after this point every tile access is wave-private (rows rbase..rbase+31)

  const int rbase = wave * 32;

  f32x4 acc1[2][8];
#pragma unroll
  for (int m = 0; m < 2; ++m)
#pragma unroll
    for (int t = 0; t < 8; ++t) acc1[m][t] = vzero;
  gemm_tile<4, 8>(tb, rbase, lane, W1f, acc1);
  epi_tile<8, true>(tb, rbase, lane, b1, acc1);  // hidden -> tile, in place

  constexpr int NT2 = NOUT / 16;
  f32x4 acc2[2][NT2];
#pragma unroll
  for (int m = 0; m < 2; ++m)
#pragma unroll
    for (int t = 0; t < NT2; ++t) acc2[m][t] = vzero;
  gemm_tile<4, NT2>(tb, rbase, lane, W2f, acc2);

#pragma unroll
  for (int t = 0; t < NT2; ++t) {
    int col = t * 16 + (lane & 15);
    float bb = b2[col];
#pragma unroll
    for (int m = 0; m < 2; ++m) {
#pragma unroll
      for (int i = 0; i < 4; ++i) {
        int row = rbase + m * 16 + (lane >> 4) * 4 + i;
        int gr = row0 + row;
        if (gr < nrows) {
          float v = acc2[m][t][i] + bb;
          if (SKIP) v += skip[(size_t)gr * NOUT + col];
          out[(size_t)gr * NOUT + col] = v;
        }
      }
    }
  }
}

// ---------- edge kernel: out = l( k(xe) + u1[src] + u2[dst] ) ----------
__global__ __launch_bounds__(256) void edge_kernel(
    const float* __restrict__ xe, const int* __restrict__ esrc,
    const int* __restrict__ edst, const float* __restrict__ u1,
    const float* __restrict__ u2, const short* __restrict__ kW1f,
    const float* __restrict__ kb1, const short* __restrict__ kW2f,
    const float* __restrict__ kb2, const short* __restrict__ lW1f,
    const float* __restrict__ lb1, const short* __restrict__ lW2f,
    const float* __restrict__ lb2, float* __restrict__ out) {
  __shared__ alignas(16) short tile[128 * 128];
  char* tb = reinterpret_cast<char*>(tile);
  const int tid = threadIdx.x;
  const int lane = tid & 63;
  const int wave = tid >> 6;
  const int e0 = blockIdx.x * 128;
  const f32x4 vzero = {0.f, 0.f, 0.f, 0.f};

  // stage xe [128][64] f32 -> bf16 (cols 0..63 of tile rows)
#pragma unroll
  for (int it = 0; it < 8; ++it) {
    int r = it * 16 + (tid >> 4);
    int f4 = tid & 15;
    float4 v = *reinterpret_cast<const float4*>(xe + (size_t)(e0 + r) * 64 + f4 * 4);
    short4 p;
    p.x = f2bf(v.x); p.y = f2bf(v.y); p.z = f2bf(v.z); p.w = f2bf(v.w);
    int off = (r * 256 + f4 * 8) ^ ((r & 7) << 4);
    *reinterpret_cast<short4*>(tb + off) = p;
  }
  __syncthreads();

  const int rbase = wave * 32;
  f32x4 acc[2][8];

  // k MLP: GEMM1 (K=64) -> relu -> tile
#pragma unroll
  for (int m = 0; m < 2; ++m)
#pragma unroll
    for (int t = 0; t < 8; ++t) acc[m][t] = vzero;
  gemm_tile<2, 8>(tb, rbase, lane, kW1f, acc);
  epi_tile<8, true>(tb, rbase, lane, kb1, acc);

  // k MLP: GEMM2 (K=128) -> tile (linear)
#pragma unroll
  for (int m = 0; m < 2; ++m)
#pragma unroll
    for (int t = 0; t < 8; ++t) acc[m][t] = vzero;
  gemm_tile<4, 8>(tb, rbase, lane, kW2f, acc);
  epi_tile<8, false>(tb, rbase, lane, kb2, acc);

  // e_hid += u1[src] + u2[dst]  (coalesced row gathers; wave-private rows)
#pragma unroll 4
  for (int rr = 0; rr < 16; ++rr) {
    int r = rbase + rr * 2 + (lane >> 5);
    int e = e0 + r;
    int s = esrc[e];
    int d = edst[e];
    int f4 = lane & 31;
    float4 va = *reinterpret_cast<const float4*>(u1 + (size_t)s * 128 + f4 * 4);
    float4 vb = *reinterpret_cast<const float4*>(u2 + (size_t)d * 128 + f4 * 4);
    int off = (r * 256 + f4 * 8) ^ ((r & 7) << 4);
    short4* p = reinterpret_cast<short4*>(tb + off);
    short4 c = *p;
    short4 nw;
    nw.x = f2bf(bf2f(c.x) + va.x + vb.x);
    nw.y = f2bf(bf2f(c.y) + va.y + vb.y);
    nw.z = f2bf(bf2f(c.z) + va.z + vb.z);
    nw.w = f2bf(bf2f(c.w) + va.w + vb.w);
    *p = nw;
  }

  // l MLP: GEMM3 (K=128) -> relu -> tile
#pragma unroll
  for (int m = 0; m < 2; ++m)
#pragma unroll
    for (int t = 0; t < 8; ++t) acc[m][t] = vzero;
  gemm_tile<4, 8>(tb, rbase, lane, lW1f, acc);
  epi_tile<8, true>(tb, rbase, lane, lb1, acc);

  // l MLP: GEMM4 (K=128, N=32) -> out
  f32x4 acc4[2][2];
#pragma unroll
  for (int m = 0; m < 2; ++m)
#pragma unroll
    for (int t = 0; t < 2; ++t) acc4[m][t] = vzero;
  gemm_tile<4, 2>(tb, rbase, lane, lW2f, acc4);

#pragma unroll
  for (int t = 0; t < 2; ++t) {
    int col = t * 16 + (lane & 15);
    float bb = lb2[col];
#pragma unroll
    for (int m = 0; m < 2; ++m) {
#pragma unroll
      for (int i = 0; i < 4; ++i) {
        int row = rbase + m * 16 + (lane >> 4) * 4 + i;
        out[(size_t)(e0 + row) * 32 + col] = acc4[m][t][i] + bb;
      }
    }
  }
}

}  // namespace

extern "C" void kernel_launch(void* const* d_in, const int* in_sizes, int n_in,
                              void* d_out, int out_size, void* d_ws, size_t ws_size,
                              hipStream_t stream) {
  const float* x = (const float*)d_in[0];
  const float* xe = (const float*)d_in[1];
  const int* eidx = (const int*)d_in[2];
  const int* esrc = eidx;
  const int* edst = eidx + NE;

  const float* fb1 = (const float*)d_in[4];
  const float* fb2 = (const float*)d_in[6];
  const float* gb1 = (const float*)d_in[8];
  const float* gb2 = (const float*)d_in[10];
  const float* hb1 = (const float*)d_in[12];
  const float* hb2 = (const float*)d_in[14];
  const float* k1b1 = (const float*)d_in[16];
  const float* k1b2 = (const float*)d_in[18];
  const float* k2b1 = (const float*)d_in[20];
  const float* k2b2 = (const float*)d_in[22];
  const float* kb1 = (const float*)d_in[24];
  const float* kb2 = (const float*)d_in[26];
  const float* lb1 = (const float*)d_in[28];
  const float* lb2 = (const float*)d_in[30];

  char* ws = (char*)d_ws;
  size_t off = 0;
  auto alloc = [&](size_t bytes) -> void* {
    void* p = ws + off;
    off = (off + bytes + 255) & ~(size_t)255;
    return p;
  };
  float* y = (float*)alloc((size_t)NN * 128 * 4);
  float* agg = (float*)alloc((size_t)NN * 128 * 4);
  float* u1 = (float*)alloc((size_t)NN * 128 * 4);
  float* u2 = (float*)alloc((size_t)NN * 128 * 4);
  int* deg = (int*)alloc((size_t)NN * 4);
  int* excl = (int*)alloc((size_t)NN * 4);
  int* bsum = (int*)alloc(256 * 4);
  int* boff = (int*)alloc(256 * 4);
  int* row_start = (int*)alloc((size_t)(NN + 16) * 4);
  int* cursor = (int*)alloc((size_t)NN * 4);
  int* adj = (int*)alloc((size_t)NE * 4);

  // weight fragment buffers
  const int wi[14] = {3, 5, 7, 9, 11, 13, 15, 17, 19, 21, 23, 25, 27, 29};
  const int wdin[14] = {128, 128, 128, 128, 128, 128, 128, 128, 128, 128, 64, 128, 128, 128};
  const int wdout[14] = {128, 128, 128, 128, 128, 64, 128, 128, 128, 128, 128, 128, 128, 32};
  short* wf[14];
  for (int i = 0; i < 14; ++i) {
    size_t elems = (size_t)wdin[i] * wdout[i];
    wf[i] = (short*)alloc(elems * 2);
    int blocks = (int)((elems + 255) / 256);
    wfrag_kernel<<<blocks, 256, 0, stream>>>((const float*)d_in[wi[i]], wf[i], wdin[i], wdout[i]);
  }
  short* fW1f = wf[0];  short* fW2f = wf[1];
  short* gW1f = wf[2];  short* gW2f = wf[3];
  short* hW1f = wf[4];  short* hW2f = wf[5];
  short* k1W1f = wf[6]; short* k1W2f = wf[7];
  short* k2W1f = wf[8]; short* k2W2f = wf[9];
  short* kW1f = wf[10]; short* kW2f = wf[11];
  short* lW1f = wf[12]; short* lW2f = wf[13];

  // CSR build
  const int nb = (NN + 255) / 256;  // 196
  hipMemsetAsync(deg, 0, (size_t)NN * 4, stream);
  hist_kernel<<<(NE + 255) / 256, 256, 0, stream>>>(edst, deg);
  scan1_kernel<<<nb, 256, 0, stream>>>(deg, excl, bsum, NN);
  scan2_kernel<<<1, 256, 0, stream>>>(bsum, boff, nb);
  scan3_kernel<<<(NN + 256) / 256 + 1, 256, 0, stream>>>(excl, boff, row_start, NN, nb);
  hipMemsetAsync(cursor, 0, (size_t)NN * 4, stream);
  fill_kernel<<<(NE + 255) / 256, 256, 0, stream>>>(esrc, edst, row_start, cursor, adj);

  const int nblk = (NN + 127) / 128;  // 391

  // y = f(x)
  mlp_node<128, false><<<nblk, 256, 0, stream>>>(x, fW1f, fb1, fW2f, fb2, nullptr, y, NN);

  // 3 message-passing steps: y = g(segment_sum(y[src], dst)) + y
  for (int s = 0; s < 3; ++s) {
    agg_kernel<<<(NN * 64 + 255) / 256, 256, 0, stream>>>(y, row_start, adj, agg);
    mlp_node<128, true><<<nblk, 256, 0, stream>>>(agg, gW1f, gb1, gW2f, gb2, y, y, NN);
  }

  // node_out = h(y)
  mlp_node<64, false><<<nblk, 256, 0, stream>>>(y, hW1f, hb1, hW2f, hb2, nullptr, (float*)d_out, NN);

  // u1 = k1(y), u2 = k2(y)
  mlp_node<128, false><<<nblk, 256, 0, stream>>>(y, k1W1f, k1b1, k1W2f, k1b2, nullptr, u1, NN);
  mlp_node<128, false><<<nblk, 256, 0, stream>>>(y, k2W1f, k2b1, k2W2f, k2b2, nullptr, u2, NN);

  // edge_out = l(k(xe) + u1[src] + u2[dst])
  float* edge_out = (float*)d_out + (size_t)NN * 64;
  edge_kernel<<<NE / 128, 256, 0, stream>>>(xe, esrc, edst, u1, u2, kW1f, kb1, kW2f, kb2,
                                            lW1f, lb1, lW2f, lb2, edge_out);
}

// Round 2
// 629.544 us; speedup vs baseline: 1.5918x; 1.5918x over previous
//
#include <hip/hip_runtime.h>
#include <hip/hip_bf16.h>

namespace {

constexpr int NN = 50000;
constexpr int NE = 800000;

typedef __attribute__((ext_vector_type(8))) short bf16x8;
typedef __attribute__((ext_vector_type(4))) float f32x4;

__device__ __forceinline__ short f2bf(float f) {
  union { __hip_bfloat16 h; short s; } u;
  u.h = __float2bfloat16(f);
  return u.s;
}
__device__ __forceinline__ float bf2f(short s) {
  union { unsigned int u; float f; } v;
  v.u = ((unsigned int)(unsigned short)s) << 16;
  return v.f;
}
__device__ __forceinline__ unsigned int pkbf2(float a, float b) {
  return (unsigned int)(unsigned short)f2bf(a) |
         ((unsigned int)(unsigned short)f2bf(b) << 16);
}

// ---------- weight repack (all 14 in one launch) ----------
// element gid = ((t*nK + kc)*64 + lane)*8 + j holds W[k][n],
//   n = t*16 + (lane&15), k = kc*32 + (lane>>4)*8 + j.
struct WTab {
  const float* W[14];
  short* out[14];
  int din[14];
  int dout[14];
};

__global__ __launch_bounds__(256) void wfrag_all(WTab tab) {
  int wi = blockIdx.y;
  int din = tab.din[wi], dout = tab.dout[wi];
  int total = din * dout;
  int gid = blockIdx.x * 256 + threadIdx.x;
  if (gid >= total) return;
  const float* W = tab.W[wi];
  short* Wf = tab.out[wi];
  int j = gid & 7;
  int l = (gid >> 3) & 63;
  int rest = gid >> 9;
  int nK = din >> 5;
  int kc = rest % nK;
  int t = rest / nK;
  int n = t * 16 + (l & 15);
  int k = kc * 32 + (l >> 4) * 8 + j;
  Wf[gid] = f2bf(W[(size_t)k * dout + n]);
}

// ---------- CSR build ----------
__global__ __launch_bounds__(256) void hist_kernel(const int* __restrict__ edst,
                                                   int* __restrict__ deg) {
  int e = blockIdx.x * 256 + threadIdx.x;
  if (e < NE) atomicAdd(&deg[edst[e]], 1);
}

__global__ __launch_bounds__(256) void scan1_kernel(const int* __restrict__ deg,
                                                    int* __restrict__ excl,
                                                    int* __restrict__ bsum, int N) {
  __shared__ int s[256];
  int tid = threadIdx.x;
  int i = blockIdx.x * 256 + tid;
  int v = (i < N) ? deg[i] : 0;
  s[tid] = v;
  __syncthreads();
  for (int d = 1; d < 256; d <<= 1) {
    int t = (tid >= d) ? s[tid - d] : 0;
    __syncthreads();
    s[tid] += t;
    __syncthreads();
  }
  if (i < N) excl[i] = s[tid] - v;
  if (tid == 255) bsum[blockIdx.x] = s[255];
}

__global__ __launch_bounds__(256) void scan2_kernel(const int* __restrict__ bsum,
                                                    int* __restrict__ boff, int nb) {
  __shared__ int s[256];
  int tid = threadIdx.x;
  int v = (tid < nb) ? bsum[tid] : 0;
  s[tid] = v;
  __syncthreads();
  for (int d = 1; d < 256; d <<= 1) {
    int t = (tid >= d) ? s[tid - d] : 0;
    __syncthreads();
    s[tid] += t;
    __syncthreads();
  }
  if (tid <= nb) boff[tid] = s[tid] - v;
}

__global__ __launch_bounds__(256) void scan3_kernel(const int* __restrict__ excl,
                                                    const int* __restrict__ boff,
                                                    int* __restrict__ row_start,
                                                    int N, int nb) {
  int i = blockIdx.x * 256 + threadIdx.x;
  if (i < N) row_start[i] = excl[i] + boff[i >> 8];
  else if (i == N) row_start[N] = boff[nb];
}

__global__ __launch_bounds__(256) void fill_kernel(const int* __restrict__ esrc,
                                                   const int* __restrict__ edst,
                                                   const int* __restrict__ row_start,
                                                   int* __restrict__ cursor,
                                                   int* __restrict__ adj) {
  int e = blockIdx.x * 256 + threadIdx.x;
  if (e >= NE) return;
  int d = edst[e];
  int p = atomicAdd(&cursor[d], 1);
  adj[row_start[d] + p] = esrc[e];
}

// ---------- segment-sum via CSR gather (bf16 in / bf16 out), one wave/node ----------
__global__ __launch_bounds__(256) void agg_kernel(const ushort* __restrict__ yb,
                                                  const int* __restrict__ row_start,
                                                  const int* __restrict__ adj,
                                                  ushort* __restrict__ aggb) {
  int gid = blockIdx.x * 256 + threadIdx.x;
  int n = gid >> 6;
  if (n >= NN) return;
  int lane = gid & 63;
  float a0 = 0.f, a1 = 0.f;
  int s0 = row_start[n], s1 = row_start[n + 1];
#pragma unroll 4
  for (int i = s0; i < s1; ++i) {
    int s = adj[i];  // wave-uniform
    unsigned int v = *reinterpret_cast<const unsigned int*>(yb + (size_t)s * 128 + lane * 2);
    a0 += bf2f((short)(v & 0xffff));
    a1 += bf2f((short)(v >> 16));
  }
  *reinterpret_cast<unsigned int*>(aggb + (size_t)n * 128 + lane * 2) = pkbf2(a0, a1);
}

// ---------- MFMA helpers ----------
// Tile: [128 rows][128 bf16 cols], row stride 256B, XOR swizzle ((row&7)<<4).
template <int NKC, int NT>
__device__ __forceinline__ void gemm_tile(const char* tb, int rbase, int lane,
                                          const short* __restrict__ Wf,
                                          f32x4 (&acc)[2][NT]) {
#pragma unroll
  for (int kc = 0; kc < NKC; ++kc) {
    bf16x8 a[2];
#pragma unroll
    for (int m = 0; m < 2; ++m) {
      int row = rbase + m * 16 + (lane & 15);
      int off = (row * 256 + kc * 64 + (lane >> 4) * 16) ^ ((row & 7) << 4);
      a[m] = *reinterpret_cast<const bf16x8*>(tb + off);
    }
#pragma unroll
    for (int t = 0; t < NT; ++t) {
      bf16x8 b = *reinterpret_cast<const bf16x8*>(Wf + (t * NKC + kc) * 512 + lane * 8);
      acc[0][t] = __builtin_amdgcn_mfma_f32_16x16x32_bf16(a[0], b, acc[0][t], 0, 0, 0);
      acc[1][t] = __builtin_amdgcn_mfma_f32_16x16x32_bf16(a[1], b, acc[1][t], 0, 0, 0);
    }
  }
}

template <int NT, bool RELU>
__device__ __forceinline__ void epi_tile(char* tb, int rbase, int lane,
                                         const float* __restrict__ bias,
                                         f32x4 (&acc)[2][NT]) {
#pragma unroll
  for (int t = 0; t < NT; ++t) {
    int col = t * 16 + (lane & 15);
    float bb = bias[col];
#pragma unroll
    for (int m = 0; m < 2; ++m) {
#pragma unroll
      for (int i = 0; i < 4; ++i) {
        int row = rbase + m * 16 + (lane >> 4) * 4 + i;
        float h = acc[m][t][i] + bb;
        if (RELU) h = fmaxf(h, 0.f);
        int off = (row * 256 + col * 2) ^ ((row & 7) << 4);
        *reinterpret_cast<short*>(tb + off) = f2bf(h);
      }
    }
  }
}

// ---------- node MLP family: out128 = [relu(X@W1+b1)]@W2+b2 (+skip) ----------
// INBF16: stage from bf16 [r][128]; SKIP/WF32: f32 y read-add / write; always
// writes bf16 result (yb_out) via in-tile repack + coalesced stores.
template <bool INBF16, bool SKIP, bool WF32>
__global__ __launch_bounds__(256) void mlp_fg(const void* __restrict__ Xv,
                                              const short* __restrict__ W1f,
                                              const float* __restrict__ b1,
                                              const short* __restrict__ W2f,
                                              const float* __restrict__ b2,
                                              float* __restrict__ y,
                                              ushort* __restrict__ yb_out,
                                              int nrows) {
  __shared__ alignas(16) short tile[128 * 128];
  char* tb = reinterpret_cast<char*>(tile);
  const int tid = threadIdx.x;
  const int lane = tid & 63;
  const int wave = tid >> 6;
  const int row0 = blockIdx.x * 128;
  const f32x4 vzero = {0.f, 0.f, 0.f, 0.f};

  if constexpr (INBF16) {
    const ushort* X = (const ushort*)Xv;
#pragma unroll
    for (int it = 0; it < 8; ++it) {
      int r = it * 16 + (tid >> 4);
      int c = tid & 15;
      int gr = row0 + r;
      bf16x8 v = {};
      if (gr < nrows) v = *reinterpret_cast<const bf16x8*>(X + (size_t)gr * 128 + c * 8);
      int off = (r * 256 + c * 16) ^ ((r & 7) << 4);
      *reinterpret_cast<bf16x8*>(tb + off) = v;
    }
  } else {
    const float* X = (const float*)Xv;
#pragma unroll
    for (int it = 0; it < 16; ++it) {
      int r = it * 8 + (tid >> 5);
      int c = tid & 31;
      int gr = row0 + r;
      float4 v = make_float4(0.f, 0.f, 0.f, 0.f);
      if (gr < nrows) v = *reinterpret_cast<const float4*>(X + (size_t)gr * 128 + c * 4);
      short4 p;
      p.x = f2bf(v.x); p.y = f2bf(v.y); p.z = f2bf(v.z); p.w = f2bf(v.w);
      int off = (r * 256 + c * 8) ^ ((r & 7) << 4);
      *reinterpret_cast<short4*>(tb + off) = p;
    }
  }
  __syncthreads();
  // all tile accesses below are wave-private rows -> no more barriers

  const int rbase = wave * 32;

  f32x4 acc[2][8];
#pragma unroll
  for (int m = 0; m < 2; ++m)
#pragma unroll
    for (int t = 0; t < 8; ++t) acc[m][t] = vzero;
  gemm_tile<4, 8>(tb, rbase, lane, W1f, acc);
  epi_tile<8, true>(tb, rbase, lane, b1, acc);

#pragma unroll
  for (int m = 0; m < 2; ++m)
#pragma unroll
    for (int t = 0; t < 8; ++t) acc[m][t] = vzero;
  gemm_tile<4, 8>(tb, rbase, lane, W2f, acc);

#pragma unroll
  for (int t = 0; t < 8; ++t) {
    int col = t * 16 + (lane & 15);
    float bb = b2[col];
#pragma unroll
    for (int m = 0; m < 2; ++m) {
#pragma unroll
      for (int i = 0; i < 4; ++i) {
        int row = rbase + m * 16 + (lane >> 4) * 4 + i;
        int gr = row0 + row;
        if (gr < nrows) {
          float v = acc[m][t][i] + bb;
          if constexpr (SKIP) v += y[(size_t)gr * 128 + col];
          if constexpr (WF32) y[(size_t)gr * 128 + col] = v;
          int off = (row * 256 + col * 2) ^ ((row & 7) << 4);
          *reinterpret_cast<short*>(tb + off) = f2bf(v);
        }
      }
    }
  }

  // coalesced bf16 store of this wave's 32 rows
#pragma unroll 4
  for (int rr = 0; rr < 32; ++rr) {
    int row = rbase + rr;
    int gr = row0 + row;
    if (gr < nrows) {
      int off = (row * 256 + lane * 4) ^ ((row & 7) << 4);
      unsigned int v = *reinterpret_cast<const unsigned int*>(tb + off);
      *reinterpret_cast<unsigned int*>(yb_out + (size_t)gr * 128 + lane * 2) = v;
    }
  }
}

// ---------- node output MLP h: NOUT=64, f32 out ----------
__global__ __launch_bounds__(256) void mlp_h(const ushort* __restrict__ X,
                                             const short* __restrict__ W1f,
                                             const float* __restrict__ b1,
                                             const short* __restrict__ W2f,
                                             const float* __restrict__ b2,
                                             float* __restrict__ out, int nrows) {
  __shared__ alignas(16) short tile[128 * 128];
  char* tb = reinterpret_cast<char*>(tile);
  const int tid = threadIdx.x;
  const int lane = tid & 63;
  const int wave = tid >> 6;
  const int row0 = blockIdx.x * 128;
  const f32x4 vzero = {0.f, 0.f, 0.f, 0.f};

#pragma unroll
  for (int it = 0; it < 8; ++it) {
    int r = it * 16 + (tid >> 4);
    int c = tid & 15;
    int gr = row0 + r;
    bf16x8 v = {};
    if (gr < nrows) v = *reinterpret_cast<const bf16x8*>(X + (size_t)gr * 128 + c * 8);
    int off = (r * 256 + c * 16) ^ ((r & 7) << 4);
    *reinterpret_cast<bf16x8*>(tb + off) = v;
  }
  __syncthreads();

  const int rbase = wave * 32;

  f32x4 acc[2][8];
#pragma unroll
  for (int m = 0; m < 2; ++m)
#pragma unroll
    for (int t = 0; t < 8; ++t) acc[m][t] = vzero;
  gemm_tile<4, 8>(tb, rbase, lane, W1f, acc);
  epi_tile<8, true>(tb, rbase, lane, b1, acc);

  f32x4 acc2[2][4];
#pragma unroll
  for (int m = 0; m < 2; ++m)
#pragma unroll
    for (int t = 0; t < 4; ++t) acc2[m][t] = vzero;
  gemm_tile<4, 4>(tb, rbase, lane, W2f, acc2);

#pragma unroll
  for (int t = 0; t < 4; ++t) {
    int col = t * 16 + (lane & 15);
    float bb = b2[col];
#pragma unroll
    for (int m = 0; m < 2; ++m) {
#pragma unroll
      for (int i = 0; i < 4; ++i) {
        int row = rbase + m * 16 + (lane >> 4) * 4 + i;
        int gr = row0 + row;
        if (gr < nrows) out[(size_t)gr * 64 + col] = acc2[m][t][i] + bb;
      }
    }
  }
}

// ---------- edge kernel: out = l( k(xe) + u1b[src] + u2b[dst] ) ----------
// Gathers are bf16 and software-prefetched: chunk-0 issued before GEMM1,
// chunk-1 before GEMM2; sums held packed in VGPRs until the post-GEMM2 RMW.
__global__ __launch_bounds__(256) void edge_kernel(
    const float* __restrict__ xe, const int* __restrict__ esrc,
    const int* __restrict__ edst, const ushort* __restrict__ u1b,
    const ushort* __restrict__ u2b,
    const short* __restrict__ kW1f, const float* __restrict__ kb1,
    const short* __restrict__ kW2f, const float* __restrict__ kb2,
    const short* __restrict__ lW1f, const float* __restrict__ lb1,
    const short* __restrict__ lW2f, const float* __restrict__ lb2,
    float* __restrict__ out) {
  __shared__ alignas(16) short tile[128 * 128];
  char* tb = reinterpret_cast<char*>(tile);
  const int tid = threadIdx.x;
  const int lane = tid & 63;
  const int wave = tid >> 6;
  const int e0 = blockIdx.x * 128;
  const int rbase = wave * 32;
  const int f4 = lane & 31;
  const int hs = lane >> 5;
  const f32x4 vzero = {0.f, 0.f, 0.f, 0.f};

  // edge endpoints for this wave's 32 rows: lane<32 -> esrc, lane>=32 -> edst
  int vint;
  {
    int e = e0 + rbase + f4;
    vint = (lane < 32) ? esrc[e] : edst[e];
  }

  // stage xe [128][64] f32 -> bf16 tile cols 0..63
#pragma unroll
  for (int it = 0; it < 8; ++it) {
    int r = it * 16 + (tid >> 4);
    int c = tid & 15;
    float4 v = *reinterpret_cast<const float4*>(xe + (size_t)(e0 + r) * 64 + c * 4);
    short4 p;
    p.x = f2bf(v.x); p.y = f2bf(v.y); p.z = f2bf(v.z); p.w = f2bf(v.w);
    int off = (r * 256 + c * 8) ^ ((r & 7) << 4);
    *reinterpret_cast<short4*>(tb + off) = p;
  }
  __syncthreads();

  // issue gather chunk0 (rows rbase + i*2 + hs, i=0..7)
  ushort4 ga0[8], gb0[8];
#pragma unroll
  for (int i = 0; i < 8; ++i) {
    int s = __shfl(vint, i * 2 + hs);
    int d = __shfl(vint, 32 + i * 2 + hs);
    ga0[i] = *reinterpret_cast<const ushort4*>(u1b + (size_t)s * 128 + f4 * 4);
    gb0[i] = *reinterpret_cast<const ushort4*>(u2b + (size_t)d * 128 + f4 * 4);
  }

  // k MLP GEMM1 (K=64) — gather chunk0 in flight underneath
  f32x4 acc[2][8];
#pragma unroll
  for (int m = 0; m < 2; ++m)
#pragma unroll
    for (int t = 0; t < 8; ++t) acc[m][t] = vzero;
  gemm_tile<2, 8>(tb, rbase, lane, kW1f, acc);
  epi_tile<8, true>(tb, rbase, lane, kb1, acc);

  // issue chunk1, then combine chunk0
  ushort4 ga1[8], gb1v[8];
#pragma unroll
  for (int i = 0; i < 8; ++i) {
    int s = __shfl(vint, (8 + i) * 2 + hs);
    int d = __shfl(vint, 32 + (8 + i) * 2 + hs);
    ga1[i] = *reinterpret_cast<const ushort4*>(u1b + (size_t)s * 128 + f4 * 4);
    gb1v[i] = *reinterpret_cast<const ushort4*>(u2b + (size_t)d * 128 + f4 * 4);
  }
  uint2 gsum[16];
#pragma unroll
  for (int i = 0; i < 8; ++i) {
    float s0 = bf2f((short)ga0[i].x) + bf2f((short)gb0[i].x);
    float s1 = bf2f((short)ga0[i].y) + bf2f((short)gb0[i].y);
    float s2 = bf2f((short)ga0[i].z) + bf2f((short)gb0[i].z);
    float s3 = bf2f((short)ga0[i].w) + bf2f((short)gb0[i].w);
    gsum[i] = make_uint2(pkbf2(s0, s1), pkbf2(s2, s3));
  }

  // k MLP GEMM2 (K=128) — gather chunk1 in flight underneath
#pragma unroll
  for (int m = 0; m < 2; ++m)
#pragma unroll
    for (int t = 0; t < 8; ++t) acc[m][t] = vzero;
  gemm_tile<4, 8>(tb, rbase, lane, kW2f, acc);
  epi_tile<8, false>(tb, rbase, lane, kb2, acc);

#pragma unroll
  for (int i = 0; i < 8; ++i) {
    float s0 = bf2f((short)ga1[i].x) + bf2f((short)gb1v[i].x);
    float s1 = bf2f((short)ga1[i].y) + bf2f((short)gb1v[i].y);
    float s2 = bf2f((short)ga1[i].z) + bf2f((short)gb1v[i].z);
    float s3 = bf2f((short)ga1[i].w) + bf2f((short)gb1v[i].w);
    gsum[8 + i] = make_uint2(pkbf2(s0, s1), pkbf2(s2, s3));
  }

  // e_hid = k2out + u1[src] + u2[dst]  (tile RMW, wave-private rows)
#pragma unroll
  for (int i = 0; i < 16; ++i) {
    int r = rbase + i * 2 + hs;
    int off = (r * 256 + f4 * 8) ^ ((r & 7) << 4);
    short4 c = *reinterpret_cast<short4*>(tb + off);
    uint2 g = gsum[i];
    short4 nw;
    nw.x = f2bf(bf2f(c.x) + bf2f((short)(g.x & 0xffff)));
    nw.y = f2bf(bf2f(c.y) + bf2f((short)(g.x >> 16)));
    nw.z = f2bf(bf2f(c.z) + bf2f((short)(g.y & 0xffff)));
    nw.w = f2bf(bf2f(c.w) + bf2f((short)(g.y >> 16)));
    *reinterpret_cast<short4*>(tb + off) = nw;
  }

  // l MLP GEMM3 (K=128) -> relu -> tile
#pragma unroll
  for (int m = 0; m < 2; ++m)
#pragma unroll
    for (int t = 0; t < 8; ++t) acc[m][t] = vzero;
  gemm_tile<4, 8>(tb, rbase, lane, lW1f, acc);
  epi_tile<8, true>(tb, rbase, lane, lb1, acc);

  // l MLP GEMM4 (K=128, N=32) -> out
  f32x4 acc4[2][2];
#pragma unroll
  for (int m = 0; m < 2; ++m)
#pragma unroll
    for (int t = 0; t < 2; ++t) acc4[m][t] = vzero;
  gemm_tile<4, 2>(tb, rbase, lane, lW2f, acc4);

#pragma unroll
  for (int t = 0; t < 2; ++t) {
    int col = t * 16 + (lane & 15);
    float bb = lb2[col];
#pragma unroll
    for (int m = 0; m < 2; ++m) {
#pragma unroll
      for (int i = 0; i < 4; ++i) {
        int row = rbase + m * 16 + (lane >> 4) * 4 + i;
        out[(size_t)(e0 + row) * 32 + col] = acc4[m][t][i] + bb;
      }
    }
  }
}

}  // namespace

extern "C" void kernel_launch(void* const* d_in, const int* in_sizes, int n_in,
                              void* d_out, int out_size, void* d_ws, size_t ws_size,
                              hipStream_t stream) {
  const float* x = (const float*)d_in[0];
  const float* xe = (const float*)d_in[1];
  const int* eidx = (const int*)d_in[2];
  const int* esrc = eidx;
  const int* edst = eidx + NE;

  const float* fb1 = (const float*)d_in[4];
  const float* fb2 = (const float*)d_in[6];
  const float* gb1 = (const float*)d_in[8];
  const float* gb2 = (const float*)d_in[10];
  const float* hb1 = (const float*)d_in[12];
  const float* hb2 = (const float*)d_in[14];
  const float* k1b1 = (const float*)d_in[16];
  const float* k1b2 = (const float*)d_in[18];
  const float* k2b1 = (const float*)d_in[20];
  const float* k2b2 = (const float*)d_in[22];
  const float* kb1 = (const float*)d_in[24];
  const float* kb2 = (const float*)d_in[26];
  const float* lb1 = (const float*)d_in[28];
  const float* lb2 = (const float*)d_in[30];

  char* ws = (char*)d_ws;
  size_t off = 0;
  auto alloc = [&](size_t bytes) -> void* {
    void* p = ws + off;
    off = (off + bytes + 255) & ~(size_t)255;
    return p;
  };
  float* y = (float*)alloc((size_t)NN * 128 * 4);
  ushort* ybA = (ushort*)alloc((size_t)NN * 128 * 2);
  ushort* ybB = (ushort*)alloc((size_t)NN * 128 * 2);
  ushort* aggb = (ushort*)alloc((size_t)NN * 128 * 2);
  ushort* u1b = (ushort*)alloc((size_t)NN * 128 * 2);
  ushort* u2b = (ushort*)alloc((size_t)NN * 128 * 2);
  int* deg = (int*)alloc((size_t)NN * 4);
  int* excl = (int*)alloc((size_t)NN * 4);
  int* bsum = (int*)alloc(256 * 4);
  int* boff = (int*)alloc(256 * 4);
  int* row_start = (int*)alloc((size_t)(NN + 16) * 4);
  int* cursor = (int*)alloc((size_t)NN * 4);
  int* adj = (int*)alloc((size_t)NE * 4);

  // weight fragment buffers (single fused repack launch)
  const int wi[14] = {3, 5, 7, 9, 11, 13, 15, 17, 19, 21, 23, 25, 27, 29};
  const int wdin[14] = {128, 128, 128, 128, 128, 128, 128, 128, 128, 128, 64, 128, 128, 128};
  const int wdout[14] = {128, 128, 128, 128, 128, 64, 128, 128, 128, 128, 128, 128, 128, 32};
  WTab tab;
  short* wf[14];
  for (int i = 0; i < 14; ++i) {
    size_t elems = (size_t)wdin[i] * wdout[i];
    wf[i] = (short*)alloc(elems * 2);
    tab.W[i] = (const float*)d_in[wi[i]];
    tab.out[i] = wf[i];
    tab.din[i] = wdin[i];
    tab.dout[i] = wdout[i];
  }
  wfrag_all<<<dim3(64, 14, 1), 256, 0, stream>>>(tab);

  short* fW1f = wf[0];  short* fW2f = wf[1];
  short* gW1f = wf[2];  short* gW2f = wf[3];
  short* hW1f = wf[4];  short* hW2f = wf[5];
  short* k1W1f = wf[6]; short* k1W2f = wf[7];
  short* k2W1f = wf[8]; short* k2W2f = wf[9];
  short* kW1f = wf[10]; short* kW2f = wf[11];
  short* lW1f = wf[12]; short* lW2f = wf[13];

  // CSR build
  const int nb = (NN + 255) / 256;  // 196
  hipMemsetAsync(deg, 0, (size_t)NN * 4, stream);
  hist_kernel<<<(NE + 255) / 256, 256, 0, stream>>>(edst, deg);
  scan1_kernel<<<nb, 256, 0, stream>>>(deg, excl, bsum, NN);
  scan2_kernel<<<1, 256, 0, stream>>>(bsum, boff, nb);
  scan3_kernel<<<(NN + 256) / 256 + 1, 256, 0, stream>>>(excl, boff, row_start, NN, nb);
  hipMemsetAsync(cursor, 0, (size_t)NN * 4, stream);
  fill_kernel<<<(NE + 255) / 256, 256, 0, stream>>>(esrc, edst, row_start, cursor, adj);

  const int nblk = (NN + 127) / 128;  // 391

  // y = f(x)  (f32 y + bf16 ybA)
  mlp_fg<false, false, true><<<nblk, 256, 0, stream>>>(x, fW1f, fb1, fW2f, fb2, y, ybA, NN);

  // 3 message-passing steps: y = g(segment_sum(yb[src], dst)) + y  (yb ping-pong)
  ushort* ybin = ybA;
  ushort* ybout = ybB;
  for (int s = 0; s < 3; ++s) {
    agg_kernel<<<(NN * 64) / 256, 256, 0, stream>>>(ybin, row_start, adj, aggb);
    mlp_fg<true, true, true><<<nblk, 256, 0, stream>>>(aggb, gW1f, gb1, gW2f, gb2, y, ybout, NN);
    ushort* t = ybin; ybin = ybout; ybout = t;
  }
  // ybin now holds the final bf16 y

  // node_out = h(y)
  mlp_h<<<nblk, 256, 0, stream>>>(ybin, hW1f, hb1, hW2f, hb2, (float*)d_out, NN);

  // u1 = k1(y), u2 = k2(y)  (bf16 outputs)
  mlp_fg<true, false, false><<<nblk, 256, 0, stream>>>(ybin, k1W1f, k1b1, k1W2f, k1b2, nullptr, u1b, NN);
  mlp_fg<true, false, false><<<nblk, 256, 0, stream>>>(ybin, k2W1f, k2b1, k2W2f, k2b2, nullptr, u2b, NN);

  // edge_out = l(k(xe) + u1[src] + u2[dst])
  float* edge_out = (float*)d_out + (size_t)NN * 64;
  edge_kernel<<<NE / 128, 256, 0, stream>>>(xe, esrc, edst, u1b, u2b, kW1f, kb1, kW2f, kb2,
                                            lW1f, lb1, lW2f, lb2, edge_out);
}

// Round 3
// 585.115 us; speedup vs baseline: 1.7126x; 1.0759x over previous
//
#include <hip/hip_runtime.h>
#include <hip/hip_bf16.h>

namespace {

constexpr int NN = 50000;
constexpr int NE = 800000;

typedef __attribute__((ext_vector_type(8))) short bf16x8;
typedef __attribute__((ext_vector_type(4))) float f32x4;

__device__ __forceinline__ short f2bf(float f) {
  union { __hip_bfloat16 h; short s; } u;
  u.h = __float2bfloat16(f);
  return u.s;
}
__device__ __forceinline__ float bf2f(short s) {
  union { unsigned int u; float f; } v;
  v.u = ((unsigned int)(unsigned short)s) << 16;
  return v.f;
}
__device__ __forceinline__ unsigned int pkbf2(float a, float b) {
  return (unsigned int)(unsigned short)f2bf(a) |
         ((unsigned int)(unsigned short)f2bf(b) << 16);
}

// ---------- weight repack (all 14 in one launch) ----------
// element gid = ((t*nK + kc)*64 + lane)*8 + j holds W[k][n],
//   n = t*16 + (lane&15), k = kc*32 + (lane>>4)*8 + j.
struct WTab {
  const float* W[14];
  short* out[14];
  int din[14];
  int dout[14];
};

__global__ __launch_bounds__(256) void wfrag_all(WTab tab) {
  int wi = blockIdx.y;
  int din = tab.din[wi], dout = tab.dout[wi];
  int total = din * dout;
  int gid = blockIdx.x * 256 + threadIdx.x;
  if (gid >= total) return;
  const float* W = tab.W[wi];
  short* Wf = tab.out[wi];
  int j = gid & 7;
  int l = (gid >> 3) & 63;
  int rest = gid >> 9;
  int nK = din >> 5;
  int kc = rest % nK;
  int t = rest / nK;
  int n = t * 16 + (l & 15);
  int k = kc * 32 + (l >> 4) * 8 + j;
  Wf[gid] = f2bf(W[(size_t)k * dout + n]);
}

// ---------- CSR build ----------
__global__ __launch_bounds__(256) void hist_kernel(const int* __restrict__ edst,
                                                   int* __restrict__ deg) {
  int e = blockIdx.x * 256 + threadIdx.x;
  if (e < NE) atomicAdd(&deg[edst[e]], 1);
}

__global__ __launch_bounds__(256) void scan1_kernel(const int* __restrict__ deg,
                                                    int* __restrict__ excl,
                                                    int* __restrict__ bsum, int N) {
  __shared__ int s[256];
  int tid = threadIdx.x;
  int i = blockIdx.x * 256 + tid;
  int v = (i < N) ? deg[i] : 0;
  s[tid] = v;
  __syncthreads();
  for (int d = 1; d < 256; d <<= 1) {
    int t = (tid >= d) ? s[tid - d] : 0;
    __syncthreads();
    s[tid] += t;
    __syncthreads();
  }
  if (i < N) excl[i] = s[tid] - v;
  if (tid == 255) bsum[blockIdx.x] = s[255];
}

__global__ __launch_bounds__(256) void scan2_kernel(const int* __restrict__ bsum,
                                                    int* __restrict__ boff, int nb) {
  __shared__ int s[256];
  int tid = threadIdx.x;
  int v = (tid < nb) ? bsum[tid] : 0;
  s[tid] = v;
  __syncthreads();
  for (int d = 1; d < 256; d <<= 1) {
    int t = (tid >= d) ? s[tid - d] : 0;
    __syncthreads();
    s[tid] += t;
    __syncthreads();
  }
  if (tid <= nb) boff[tid] = s[tid] - v;
}

__global__ __launch_bounds__(256) void scan3_kernel(const int* __restrict__ excl,
                                                    const int* __restrict__ boff,
                                                    int* __restrict__ row_start,
                                                    int N, int nb) {
  int i = blockIdx.x * 256 + threadIdx.x;
  if (i < N) row_start[i] = excl[i] + boff[i >> 8];
  else if (i == N) row_start[N] = boff[nb];
}

__global__ __launch_bounds__(256) void fill_kernel(const int* __restrict__ esrc,
                                                   const int* __restrict__ edst,
                                                   const int* __restrict__ row_start,
                                                   int* __restrict__ cursor,
                                                   int* __restrict__ adj) {
  int e = blockIdx.x * 256 + threadIdx.x;
  if (e >= NE) return;
  int d = edst[e];
  int p = atomicAdd(&cursor[d], 1);
  adj[row_start[d] + p] = esrc[e];
}

// ---------- segment-sum: 4 nodes/wave, 16 lanes per node ----------
// Cooperative adj load (16-wide) + shfl broadcast -> all row gathers for a
// 16-neighbor batch are independent and in flight together.
__global__ __launch_bounds__(256) void agg_kernel(const ushort* __restrict__ yb,
                                                  const int* __restrict__ row_start,
                                                  const int* __restrict__ adj,
                                                  ushort* __restrict__ aggb) {
  int gid = blockIdx.x * 256 + threadIdx.x;
  int lane = gid & 63;
  int g = lane >> 4;
  int q = lane & 15;
  int n = (gid >> 6) * 4 + g;  // NN % 4 == 0, grid exact -> n < NN
  int s0 = row_start[n], s1 = row_start[n + 1];
  float a0 = 0, a1 = 0, a2 = 0, a3 = 0, a4 = 0, a5 = 0, a6 = 0, a7 = 0;
  for (int base = s0; base < s1; base += 16) {
    int idx = 0;
    if (base + q < s1) idx = adj[base + q];
    int cnt = s1 - base;
    if (cnt > 16) cnt = 16;
#pragma unroll
    for (int j = 0; j < 16; ++j) {
      if (j < cnt) {
        int s = __shfl(idx, g * 16 + j);
        uint4 v = *reinterpret_cast<const uint4*>(yb + (size_t)s * 128 + q * 8);
        a0 += bf2f((short)(v.x & 0xffff)); a1 += bf2f((short)(v.x >> 16));
        a2 += bf2f((short)(v.y & 0xffff)); a3 += bf2f((short)(v.y >> 16));
        a4 += bf2f((short)(v.z & 0xffff)); a5 += bf2f((short)(v.z >> 16));
        a6 += bf2f((short)(v.w & 0xffff)); a7 += bf2f((short)(v.w >> 16));
      }
    }
  }
  uint4 o;
  o.x = pkbf2(a0, a1);
  o.y = pkbf2(a2, a3);
  o.z = pkbf2(a4, a5);
  o.w = pkbf2(a6, a7);
  *reinterpret_cast<uint4*>(aggb + (size_t)n * 128 + q * 8) = o;
}

// ---------- MFMA helpers ----------
// Tile: [rows][128 bf16 cols], row stride 256B, XOR swizzle ((row&7)<<4).
// gemm_pipe: B-fragment software pipeline (double-buffered global loads).
template <int NM, int NKC, int NT>
__device__ __forceinline__ void gemm_pipe(const char* tb, int rbase, int lane,
                                          const short* __restrict__ Wf,
                                          f32x4 (&acc)[NM][NT]) {
  bf16x8 bcur[NT];
#pragma unroll
  for (int t = 0; t < NT; ++t)
    bcur[t] = *reinterpret_cast<const bf16x8*>(Wf + (t * NKC) * 512 + lane * 8);
#pragma unroll
  for (int kc = 0; kc < NKC; ++kc) {
    bf16x8 a[NM];
#pragma unroll
    for (int m = 0; m < NM; ++m) {
      int row = rbase + m * 16 + (lane & 15);
      int off = (row * 256 + kc * 64 + (lane >> 4) * 16) ^ ((row & 7) << 4);
      a[m] = *reinterpret_cast<const bf16x8*>(tb + off);
    }
    bf16x8 bnext[NT];
    if (kc + 1 < NKC) {
#pragma unroll
      for (int t = 0; t < NT; ++t)
        bnext[t] = *reinterpret_cast<const bf16x8*>(Wf + (t * NKC + kc + 1) * 512 + lane * 8);
    }
#pragma unroll
    for (int t = 0; t < NT; ++t)
#pragma unroll
      for (int m = 0; m < NM; ++m)
        acc[m][t] = __builtin_amdgcn_mfma_f32_16x16x32_bf16(a[m], bcur[t], acc[m][t], 0, 0, 0);
    if (kc + 1 < NKC) {
#pragma unroll
      for (int t = 0; t < NT; ++t) bcur[t] = bnext[t];
    }
  }
}

template <int NM, int NT>
__device__ __forceinline__ void zero_acc(f32x4 (&acc)[NM][NT]) {
  const f32x4 vzero = {0.f, 0.f, 0.f, 0.f};
#pragma unroll
  for (int m = 0; m < NM; ++m)
#pragma unroll
    for (int t = 0; t < NT; ++t) acc[m][t] = vzero;
}

// epilogue: acc (+bias, relu) -> bf16 into dst LDS region (swizzled)
template <int NM, int NT, bool RELU>
__device__ __forceinline__ void epi_tile(char* dst, int rbase, int lane,
                                         const float* __restrict__ bias,
                                         f32x4 (&acc)[NM][NT]) {
#pragma unroll
  for (int t = 0; t < NT; ++t) {
    int col = t * 16 + (lane & 15);
    float bb = bias[col];
#pragma unroll
    for (int m = 0; m < NM; ++m) {
#pragma unroll
      for (int i = 0; i < 4; ++i) {
        int row = rbase + m * 16 + (lane >> 4) * 4 + i;
        float h = acc[m][t][i] + bb;
        if (RELU) h = fmaxf(h, 0.f);
        int off = (row * 256 + col * 2) ^ ((row & 7) << 4);
        *reinterpret_cast<short*>(dst + off) = f2bf(h);
      }
    }
  }
}

// ---------- node MLP f/g: 64-row tiles; y f32 skip/write + bf16 out ----------
template <bool INBF16, bool SKIP>
__global__ __launch_bounds__(256, 3) void mlp_fg(const void* __restrict__ Xv,
                                                 const short* __restrict__ W1f,
                                                 const float* __restrict__ b1,
                                                 const short* __restrict__ W2f,
                                                 const float* __restrict__ b2,
                                                 float* __restrict__ y,
                                                 ushort* __restrict__ yb_out,
                                                 int nrows) {
  __shared__ alignas(16) short tile[64 * 128];
  __shared__ alignas(16) short hid[64 * 128];
  char* tb = reinterpret_cast<char*>(tile);
  char* hb = reinterpret_cast<char*>(hid);
  const int tid = threadIdx.x;
  const int lane = tid & 63;
  const int wave = tid >> 6;
  const int row0 = blockIdx.x * 64;

  if constexpr (INBF16) {
    const ushort* X = (const ushort*)Xv;
#pragma unroll
    for (int it = 0; it < 4; ++it) {
      int r = it * 16 + (tid >> 4);
      int c = tid & 15;
      int gr = row0 + r;
      bf16x8 v = {};
      if (gr < nrows) v = *reinterpret_cast<const bf16x8*>(X + (size_t)gr * 128 + c * 8);
      int off = (r * 256 + c * 16) ^ ((r & 7) << 4);
      *reinterpret_cast<bf16x8*>(tb + off) = v;
    }
  } else {
    const float* X = (const float*)Xv;
#pragma unroll
    for (int it = 0; it < 8; ++it) {
      int r = it * 8 + (tid >> 5);
      int c = tid & 31;
      int gr = row0 + r;
      float4 v = make_float4(0.f, 0.f, 0.f, 0.f);
      if (gr < nrows) v = *reinterpret_cast<const float4*>(X + (size_t)gr * 128 + c * 4);
      short4 p;
      p.x = f2bf(v.x); p.y = f2bf(v.y); p.z = f2bf(v.z); p.w = f2bf(v.w);
      int off = (r * 256 + c * 8) ^ ((r & 7) << 4);
      *reinterpret_cast<short4*>(tb + off) = p;
    }
  }
  __syncthreads();
  // wave-private rows from here on

  const int rbase = wave * 16;

  f32x4 acc[1][8];
  zero_acc(acc);
  gemm_pipe<1, 4, 8>(tb, rbase, lane, W1f, acc);
  epi_tile<1, 8, true>(hb, rbase, lane, b1, acc);

  zero_acc(acc);
  gemm_pipe<1, 4, 8>(hb, rbase, lane, W2f, acc);

#pragma unroll
  for (int t = 0; t < 8; ++t) {
    int col = t * 16 + (lane & 15);
    float bb = b2[col];
#pragma unroll
    for (int i = 0; i < 4; ++i) {
      int row = rbase + (lane >> 4) * 4 + i;
      int gr = row0 + row;
      if (gr < nrows) {
        float v = acc[0][t][i] + bb;
        if constexpr (SKIP) v += y[(size_t)gr * 128 + col];
        y[(size_t)gr * 128 + col] = v;
        int off = (row * 256 + col * 2) ^ ((row & 7) << 4);
        *reinterpret_cast<short*>(hb + off) = f2bf(v);
      }
    }
  }

  // coalesced bf16 store of this wave's 16 rows
#pragma unroll
  for (int rr = 0; rr < 16; ++rr) {
    int row = rbase + rr;
    int gr = row0 + row;
    if (gr < nrows) {
      int off = (row * 256 + lane * 4) ^ ((row & 7) << 4);
      unsigned int v = *reinterpret_cast<const unsigned int*>(hb + off);
      *reinterpret_cast<unsigned int*>(yb_out + (size_t)gr * 128 + lane * 2) = v;
    }
  }
}

// ---------- merged tail: u1 = k1(y), u2 = k2(y), node_out = h(y) ----------
// One staging of y serves all three MLPs (y-tile stays intact; hid reused).
__global__ __launch_bounds__(256, 3) void mlp_tail(
    const ushort* __restrict__ X,
    const short* __restrict__ k1W1f, const float* __restrict__ k1b1,
    const short* __restrict__ k1W2f, const float* __restrict__ k1b2,
    const short* __restrict__ k2W1f, const float* __restrict__ k2b1,
    const short* __restrict__ k2W2f, const float* __restrict__ k2b2,
    const short* __restrict__ hW1f, const float* __restrict__ hb1,
    const short* __restrict__ hW2f, const float* __restrict__ hb2,
    ushort* __restrict__ u1b, ushort* __restrict__ u2b,
    float* __restrict__ node_out, int nrows) {
  __shared__ alignas(16) short ytile[64 * 128];
  __shared__ alignas(16) short hid[64 * 128];
  char* tb = reinterpret_cast<char*>(ytile);
  char* hb = reinterpret_cast<char*>(hid);
  const int tid = threadIdx.x;
  const int lane = tid & 63;
  const int wave = tid >> 6;
  const int row0 = blockIdx.x * 64;

#pragma unroll
  for (int it = 0; it < 4; ++it) {
    int r = it * 16 + (tid >> 4);
    int c = tid & 15;
    int gr = row0 + r;
    bf16x8 v = {};
    if (gr < nrows) v = *reinterpret_cast<const bf16x8*>(X + (size_t)gr * 128 + c * 8);
    int off = (r * 256 + c * 16) ^ ((r & 7) << 4);
    *reinterpret_cast<bf16x8*>(tb + off) = v;
  }
  __syncthreads();

  const int rbase = wave * 16;
  f32x4 acc[1][8];

  // ---- k1 -> u1b, k2 -> u2b ----
#pragma unroll
  for (int which = 0; which < 2; ++which) {
    const short* W1f = which ? k2W1f : k1W1f;
    const float* b1 = which ? k2b1 : k1b1;
    const short* W2f = which ? k2W2f : k1W2f;
    const float* b2 = which ? k2b2 : k1b2;
    ushort* ub = which ? u2b : u1b;

    zero_acc(acc);
    gemm_pipe<1, 4, 8>(tb, rbase, lane, W1f, acc);
    epi_tile<1, 8, true>(hb, rbase, lane, b1, acc);

    zero_acc(acc);
    gemm_pipe<1, 4, 8>(hb, rbase, lane, W2f, acc);
    epi_tile<1, 8, false>(hb, rbase, lane, b2, acc);

#pragma unroll
    for (int rr = 0; rr < 16; ++rr) {
      int row = rbase + rr;
      int gr = row0 + row;
      if (gr < nrows) {
        int off = (row * 256 + lane * 4) ^ ((row & 7) << 4);
        unsigned int v = *reinterpret_cast<const unsigned int*>(hb + off);
        *reinterpret_cast<unsigned int*>(ub + (size_t)gr * 128 + lane * 2) = v;
      }
    }
  }

  // ---- h -> node_out (f32, 64 cols) ----
  zero_acc(acc);
  gemm_pipe<1, 4, 8>(tb, rbase, lane, hW1f, acc);
  epi_tile<1, 8, true>(hb, rbase, lane, hb1, acc);

  f32x4 acc2[1][4];
  zero_acc(acc2);
  gemm_pipe<1, 4, 4>(hb, rbase, lane, hW2f, acc2);

#pragma unroll
  for (int t = 0; t < 4; ++t) {
    int col = t * 16 + (lane & 15);
    float bb = hb2[col];
#pragma unroll
    for (int i = 0; i < 4; ++i) {
      int row = rbase + (lane >> 4) * 4 + i;
      int gr = row0 + row;
      if (gr < nrows) node_out[(size_t)gr * 64 + col] = acc2[0][t][i] + bb;
    }
  }
}

// ---------- edge kernel: out = l( k(xe) + u1b[src] + u2b[dst] ) ----------
__global__ __launch_bounds__(256, 2) void edge_kernel(
    const float* __restrict__ xe, const int* __restrict__ esrc,
    const int* __restrict__ edst, const ushort* __restrict__ u1b,
    const ushort* __restrict__ u2b,
    const short* __restrict__ kW1f, const float* __restrict__ kb1,
    const short* __restrict__ kW2f, const float* __restrict__ kb2,
    const short* __restrict__ lW1f, const float* __restrict__ lb1,
    const short* __restrict__ lW2f, const float* __restrict__ lb2,
    float* __restrict__ out) {
  __shared__ alignas(16) short tile[128 * 128];
  char* tb = reinterpret_cast<char*>(tile);
  const int tid = threadIdx.x;
  const int lane = tid & 63;
  const int wave = tid >> 6;
  const int e0 = blockIdx.x * 128;
  const int rbase = wave * 32;
  const int f4 = lane & 31;
  const int hs = lane >> 5;

  // edge endpoints for this wave's 32 rows: lane<32 -> esrc, lane>=32 -> edst
  int vint;
  {
    int e = e0 + rbase + f4;
    vint = (lane < 32) ? esrc[e] : edst[e];
  }

  // stage xe [128][64] f32 -> bf16 tile cols 0..63
#pragma unroll
  for (int it = 0; it < 8; ++it) {
    int r = it * 16 + (tid >> 4);
    int c = tid & 15;
    float4 v = *reinterpret_cast<const float4*>(xe + (size_t)(e0 + r) * 64 + c * 4);
    short4 p;
    p.x = f2bf(v.x); p.y = f2bf(v.y); p.z = f2bf(v.z); p.w = f2bf(v.w);
    int off = (r * 256 + c * 8) ^ ((r & 7) << 4);
    *reinterpret_cast<short4*>(tb + off) = p;
  }
  __syncthreads();

  // issue gather chunk0 (rows rbase + i*2 + hs, i=0..7)
  ushort4 ga0[8], gb0[8];
#pragma unroll
  for (int i = 0; i < 8; ++i) {
    int s = __shfl(vint, i * 2 + hs);
    int d = __shfl(vint, 32 + i * 2 + hs);
    ga0[i] = *reinterpret_cast<const ushort4*>(u1b + (size_t)s * 128 + f4 * 4);
    gb0[i] = *reinterpret_cast<const ushort4*>(u2b + (size_t)d * 128 + f4 * 4);
  }

  // k MLP GEMM1 (K=64) — gather chunk0 in flight underneath
  f32x4 acc[2][8];
  zero_acc(acc);
  gemm_pipe<2, 2, 8>(tb, rbase, lane, kW1f, acc);
  epi_tile<2, 8, true>(tb, rbase, lane, kb1, acc);

  // issue chunk1, then combine chunk0
  ushort4 ga1[8], gb1v[8];
#pragma unroll
  for (int i = 0; i < 8; ++i) {
    int s = __shfl(vint, (8 + i) * 2 + hs);
    int d = __shfl(vint, 32 + (8 + i) * 2 + hs);
    ga1[i] = *reinterpret_cast<const ushort4*>(u1b + (size_t)s * 128 + f4 * 4);
    gb1v[i] = *reinterpret_cast<const ushort4*>(u2b + (size_t)d * 128 + f4 * 4);
  }
  uint2 gsum[16];
#pragma unroll
  for (int i = 0; i < 8; ++i) {
    float s0 = bf2f((short)ga0[i].x) + bf2f((short)gb0[i].x);
    float s1 = bf2f((short)ga0[i].y) + bf2f((short)gb0[i].y);
    float s2 = bf2f((short)ga0[i].z) + bf2f((short)gb0[i].z);
    float s3 = bf2f((short)ga0[i].w) + bf2f((short)gb0[i].w);
    gsum[i] = make_uint2(pkbf2(s0, s1), pkbf2(s2, s3));
  }

  // k MLP GEMM2 (K=128) — gather chunk1 in flight underneath
  zero_acc(acc);
  gemm_pipe<2, 4, 8>(tb, rbase, lane, kW2f, acc);
  epi_tile<2, 8, false>(tb, rbase, lane, kb2, acc);

#pragma unroll
  for (int i = 0; i < 8; ++i) {
    float s0 = bf2f((short)ga1[i].x) + bf2f((short)gb1v[i].x);
    float s1 = bf2f((short)ga1[i].y) + bf2f((short)gb1v[i].y);
    float s2 = bf2f((short)ga1[i].z) + bf2f((short)gb1v[i].z);
    float s3 = bf2f((short)ga1[i].w) + bf2f((short)gb1v[i].w);
    gsum[8 + i] = make_uint2(pkbf2(s0, s1), pkbf2(s2, s3));
  }

  // e_hid = k2out + u1[src] + u2[dst]  (tile RMW, wave-private rows)
#pragma unroll
  for (int i = 0; i < 16; ++i) {
    int r = rbase + i * 2 + hs;
    int off = (r * 256 + f4 * 8) ^ ((r & 7) << 4);
    short4 c = *reinterpret_cast<short4*>(tb + off);
    uint2 g = gsum[i];
    short4 nw;
    nw.x = f2bf(bf2f(c.x) + bf2f((short)(g.x & 0xffff)));
    nw.y = f2bf(bf2f(c.y) + bf2f((short)(g.x >> 16)));
    nw.z = f2bf(bf2f(c.z) + bf2f((short)(g.y & 0xffff)));
    nw.w = f2bf(bf2f(c.w) + bf2f((short)(g.y >> 16)));
    *reinterpret_cast<short4*>(tb + off) = nw;
  }

  // l MLP GEMM3 (K=128) -> relu -> tile
  zero_acc(acc);
  gemm_pipe<2, 4, 8>(tb, rbase, lane, lW1f, acc);
  epi_tile<2, 8, true>(tb, rbase, lane, lb1, acc);

  // l MLP GEMM4 (K=128, N=32) -> out
  f32x4 acc4[2][2];
  zero_acc(acc4);
  gemm_pipe<2, 4, 2>(tb, rbase, lane, lW2f, acc4);

#pragma unroll
  for (int t = 0; t < 2; ++t) {
    int col = t * 16 + (lane & 15);
    float bb = lb2[col];
#pragma unroll
    for (int m = 0; m < 2; ++m) {
#pragma unroll
      for (int i = 0; i < 4; ++i) {
        int row = rbase + m * 16 + (lane >> 4) * 4 + i;
        out[(size_t)(e0 + row) * 32 + col] = acc4[m][t][i] + bb;
      }
    }
  }
}

}  // namespace

extern "C" void kernel_launch(void* const* d_in, const int* in_sizes, int n_in,
                              void* d_out, int out_size, void* d_ws, size_t ws_size,
                              hipStream_t stream) {
  const float* x = (const float*)d_in[0];
  const float* xe = (const float*)d_in[1];
  const int* eidx = (const int*)d_in[2];
  const int* esrc = eidx;
  const int* edst = eidx + NE;

  const float* fb1 = (const float*)d_in[4];
  const float* fb2 = (const float*)d_in[6];
  const float* gb1 = (const float*)d_in[8];
  const float* gb2 = (const float*)d_in[10];
  const float* hb1 = (const float*)d_in[12];
  const float* hb2 = (const float*)d_in[14];
  const float* k1b1 = (const float*)d_in[16];
  const float* k1b2 = (const float*)d_in[18];
  const float* k2b1 = (const float*)d_in[20];
  const float* k2b2 = (const float*)d_in[22];
  const float* kb1 = (const float*)d_in[24];
  const float* kb2 = (const float*)d_in[26];
  const float* lb1 = (const float*)d_in[28];
  const float* lb2 = (const float*)d_in[30];

  char* ws = (char*)d_ws;
  size_t off = 0;
  auto alloc = [&](size_t bytes) -> void* {
    void* p = ws + off;
    off = (off + bytes + 255) & ~(size_t)255;
    return p;
  };
  float* y = (float*)alloc((size_t)NN * 128 * 4);
  ushort* ybA = (ushort*)alloc((size_t)NN * 128 * 2);
  ushort* ybB = (ushort*)alloc((size_t)NN * 128 * 2);
  ushort* aggb = (ushort*)alloc((size_t)NN * 128 * 2);
  ushort* u1b = (ushort*)alloc((size_t)NN * 128 * 2);
  ushort* u2b = (ushort*)alloc((size_t)NN * 128 * 2);
  int* deg = (int*)alloc((size_t)NN * 4);
  int* excl = (int*)alloc((size_t)NN * 4);
  int* bsum = (int*)alloc(256 * 4);
  int* boff = (int*)alloc(256 * 4);
  int* row_start = (int*)alloc((size_t)(NN + 16) * 4);
  int* cursor = (int*)alloc((size_t)NN * 4);
  int* adj = (int*)alloc((size_t)NE * 4);

  // weight fragment buffers (single fused repack launch)
  const int wi[14] = {3, 5, 7, 9, 11, 13, 15, 17, 19, 21, 23, 25, 27, 29};
  const int wdin[14] = {128, 128, 128, 128, 128, 128, 128, 128, 128, 128, 64, 128, 128, 128};
  const int wdout[14] = {128, 128, 128, 128, 128, 64, 128, 128, 128, 128, 128, 128, 128, 32};
  WTab tab;
  short* wf[14];
  for (int i = 0; i < 14; ++i) {
    size_t elems = (size_t)wdin[i] * wdout[i];
    wf[i] = (short*)alloc(elems * 2);
    tab.W[i] = (const float*)d_in[wi[i]];
    tab.out[i] = wf[i];
    tab.din[i] = wdin[i];
    tab.dout[i] = wdout[i];
  }
  wfrag_all<<<dim3(64, 14, 1), 256, 0, stream>>>(tab);

  short* fW1f = wf[0];  short* fW2f = wf[1];
  short* gW1f = wf[2];  short* gW2f = wf[3];
  short* hW1f = wf[4];  short* hW2f = wf[5];
  short* k1W1f = wf[6]; short* k1W2f = wf[7];
  short* k2W1f = wf[8]; short* k2W2f = wf[9];
  short* kW1f = wf[10]; short* kW2f = wf[11];
  short* lW1f = wf[12]; short* lW2f = wf[13];

  // CSR build
  const int nb = (NN + 255) / 256;  // 196
  hipMemsetAsync(deg, 0, (size_t)NN * 4, stream);
  hist_kernel<<<(NE + 255) / 256, 256, 0, stream>>>(edst, deg);
  scan1_kernel<<<nb, 256, 0, stream>>>(deg, excl, bsum, NN);
  scan2_kernel<<<1, 256, 0, stream>>>(bsum, boff, nb);
  scan3_kernel<<<(NN + 256) / 256 + 1, 256, 0, stream>>>(excl, boff, row_start, NN, nb);
  hipMemsetAsync(cursor, 0, (size_t)NN * 4, stream);
  fill_kernel<<<(NE + 255) / 256, 256, 0, stream>>>(esrc, edst, row_start, cursor, adj);

  const int nblk64 = (NN + 63) / 64;  // 782

  // y = f(x)  (f32 y + bf16 ybA)
  mlp_fg<false, false><<<nblk64, 256, 0, stream>>>(x, fW1f, fb1, fW2f, fb2, y, ybA, NN);

  // 3 message-passing steps: y = g(segment_sum(yb[src], dst)) + y  (yb ping-pong)
  ushort* ybin = ybA;
  ushort* ybout = ybB;
  for (int s = 0; s < 3; ++s) {
    agg_kernel<<<(NN / 4 * 64) / 256, 256, 0, stream>>>(ybin, row_start, adj, aggb);
    mlp_fg<true, true><<<nblk64, 256, 0, stream>>>(aggb, gW1f, gb1, gW2f, gb2, y, ybout, NN);
    ushort* t = ybin; ybin = ybout; ybout = t;
  }
  // ybin now holds the final bf16 y

  // u1 = k1(y), u2 = k2(y), node_out = h(y)  — one kernel, one staging
  mlp_tail<<<nblk64, 256, 0, stream>>>(ybin, k1W1f, k1b1, k1W2f, k1b2,
                                       k2W1f, k2b1, k2W2f, k2b2,
                                       hW1f, hb1, hW2f, hb2,
                                       u1b, u2b, (float*)d_out, NN);

  // edge_out = l(k(xe) + u1[src] + u2[dst])
  float* edge_out = (float*)d_out + (size_t)NN * 64;
  edge_kernel<<<NE / 128, 256, 0, stream>>>(xe, esrc, edst, u1b, u2b, kW1f, kb1, kW2f, kb2,
                                            lW1f, lb1, lW2f, lb2, edge_out);
}